// Round 12
// baseline (411.226 us; speedup 1.0000x reference)
//
#include <hip/hip_runtime.h>

// ---------------------------------------------------------------------------
// ContrastiveLoss: loss = mean_i [ 0.5*(LSE_row_i + LSE_col_i) - diag_i ]
// over logits = normalize(img) @ normalize(txt)^T / 0.07, N=8192, D=1024.
// |logit| <= 14.29 -> exp() safe in fp32, no max subtraction needed.
//
// R11 = R10 (zero-conflict MX-fp8 16x16x128, GEMM 103.8us) +
//  (a) XCD-aware 8x8 super-tile swizzle: per-XCD L2 working set ~2MB < 4MB
//      -> staging hits L2, shortens the barrier drain that paces the 8-iter
//      K-loop (R10 analysis: latency-bound, MfmaUtil 27%/VALU 29% both idle).
//  (b) final_reduce fused into GEMM via completion counter (last block
//      reduces with agent-scope loads; threadfence release/acquire).
//  (c) normalize does the chunk interleave in-register via __shfl and stores
//      contiguously (R10 scattered 4B dword stores).
// Carried lessons: R10 - two-window LDS reads with quad pairs at identical
// in-window offsets 8192 apart collide (+2cyc/b128); producer-side even/odd
// chunk interleave restores the R5 zero-conflict geometry. R8 - no-LDS
// thrashes L1. R9 - occupancy not the limiter. R4 - only b128 LDS reads are
// conflict-free under the 16B swizzle. R1 - staging lane->addr must stay
// segment-monotone per quarter-wave.
// ---------------------------------------------------------------------------

#define BM 128
#define BN 128
#define BKB 128   // fp8 K-bytes per iteration (one MFMA k-step)

typedef float floatx4 __attribute__((ext_vector_type(4)));
typedef int   intx4   __attribute__((ext_vector_type(4)));
typedef int   intx8   __attribute__((ext_vector_type(8)));

__device__ __forceinline__ void gload_lds16(const unsigned char* g, unsigned char* lds) {
    __builtin_amdgcn_global_load_lds(
        (const __attribute__((address_space(1))) void*)g,
        (__attribute__((address_space(3))) void*)lds,
        16, 0, 0);
}

// ---- Kernel 1: row L2-normalize, x16, fp32 -> fp8 e4m3, interleaved --------
// One wave per row (16 floats/lane), 4 rows per block. Rows [0,N)->img,
// [N,2N)->txt. Chunk interleave done in-register: lane l stores contiguous
// dword j*64+l holding the value of source dword j*64+src, src =
// (l&32)|(c'<<2)|(l&3), c' = ((p&3)<<1)|(p>>2), p=(l>>2)&7  (R10 mapping:
// even 16B chunks -> first 64B half, odd -> second).
// Side duty: zero rowsum/colsum (2N floats), out, and the completion counter.
__global__ __launch_bounds__(256)
void normalize_fp8(const float* __restrict__ img, const float* __restrict__ txt,
                   unsigned int* __restrict__ oimg, unsigned int* __restrict__ otxt,
                   float* __restrict__ sums, int* __restrict__ counter,
                   float* __restrict__ out, int N) {
    const int gi = blockIdx.x * 256 + threadIdx.x;
    if (gi < 2 * N) sums[gi] = 0.f;
    if (gi == 0) { out[0] = 0.f; *counter = 0; }

    const int gw = blockIdx.x * 4 + (threadIdx.x >> 6);   // row id in [0,2N)
    const int lane = threadIdx.x & 63;
    const float* in = (gw < N) ? img : txt;
    unsigned int* o = (gw < N) ? oimg : otxt;
    const int row = (gw < N) ? gw : gw - N;
    const float4* rp = (const float4*)(in + (size_t)row * 1024);

    float4 v[4];
    float ss = 0.f;
    #pragma unroll
    for (int j = 0; j < 4; ++j) {
        v[j] = rp[j * 64 + lane];
        ss += v[j].x * v[j].x + v[j].y * v[j].y + v[j].z * v[j].z + v[j].w * v[j].w;
    }
    #pragma unroll
    for (int o2 = 1; o2 < 64; o2 <<= 1) ss += __shfl_xor(ss, o2);
    const float inv = 16.0f / fmaxf(sqrtf(ss), 1e-8f);   // x16 quantization scale

    const int p8 = (lane >> 2) & 7;
    const int csrc = ((p8 & 3) << 1) | (p8 >> 2);
    const int src = (lane & 32) | (csrc << 2) | (lane & 3);

    #pragma unroll
    for (int j = 0; j < 4; ++j) {
        int p = __builtin_amdgcn_cvt_pk_fp8_f32(v[j].x * inv, v[j].y * inv, 0, false);
        p = __builtin_amdgcn_cvt_pk_fp8_f32(v[j].z * inv, v[j].w * inv, p, true);
        const int ps = __shfl(p, src);
        o[(size_t)row * 256 + j * 64 + lane] = (unsigned int)ps;
    }
}

// ---- Kernel 2: NT MX-fp8 GEMM + fused exp/sums/diag + last-block reduce ----
__global__ __launch_bounds__(256)
void gemm_exp_kernel(const unsigned char* __restrict__ A,   // img_q [N][K] fp8 (interleaved)
                     const unsigned char* __restrict__ B,   // txt_q [N][K] fp8 (interleaved)
                     float* __restrict__ rowsum, float* __restrict__ colsum,
                     float* __restrict__ diag, int* __restrict__ counter,
                     float* __restrict__ out, int N, int K, float scale) {
    // XCD swizzle: 8x8 super-tiles. id&7 ~ XCD; per 8 consecutive groups each
    // XCD sees 8 A-panels + 8 B-panels (~2MB) -> L2-resident staging.
    const int id = blockIdx.x;
    const int group = id >> 6, local = id & 63;
    const int bm = (group & 7) * 8 + (local & 7);
    const int bn = (group >> 3) * 8 + (local >> 3);

    __shared__ unsigned char As[2 * BM * 64];   // 16 KB
    __shared__ unsigned char Bs[2 * BN * 64];   // 16 KB

    const int tid = threadIdx.x;
    const int lane = tid & 63;
    const int wave = tid >> 6;
    const int quad = lane >> 4;
    const int lanelo = lane & 15;
    const int wrow = (wave >> 1) * 64;   // wave quadrant within 128x128
    const int wcol = (wave & 1) * 64;

    floatx4 acc[4][4] = {};

    // Staging (R7 pattern): chunk c = wave*128 + lane (and +64); LDS slot =
    // c&3 of row c>>2; global chunk fetched = slot ^ swz(row).
    const int c0 = wave * 128 + lane;
    const int c1 = c0 + 64;
    const int r0 = c0 >> 2, r1 = c1 >> 2;
    const int kg0 = ((c0 & 3) ^ ((r0 >> 1) & 3)) * 16;   // byte in 64B window
    const int kg1 = ((c1 & 3) ^ ((r1 >> 1) & 3)) * 16;

    const unsigned char* pa0 = A + (size_t)bm * BM * K + (size_t)r0 * K + kg0;
    const unsigned char* pa1 = A + (size_t)bm * BM * K + (size_t)r1 * K + kg1;
    const unsigned char* pb0 = B + (size_t)bn * BN * K + (size_t)r0 * K + kg0;
    const unsigned char* pb1 = B + (size_t)bn * BN * K + (size_t)r1 * K + kg1;
    unsigned char* dA0 = As + c0 * 16;
    unsigned char* dA1 = As + c1 * 16;
    unsigned char* dB0 = Bs + c0 * 16;
    unsigned char* dB1 = Bs + c1 * 16;

    // Fragment LDS offsets (R5 geometry): slot = quad ^ swz(R) of one 64B
    // window; read1 = even chunks (k[32q..32q+16)), read2 = +8192 (odd).
    int aoff[4], boff[4];
    #pragma unroll
    for (int t = 0; t < 4; ++t) {
        const int Ra = wrow + t * 16 + lanelo;
        const int Rb = wcol + t * 16 + lanelo;
        aoff[t] = Ra * 64 + ((quad ^ ((Ra >> 1) & 3)) * 16);
        boff[t] = Rb * 64 + ((quad ^ ((Rb >> 1) & 3)) * 16);
    }

    for (int k0 = 0; k0 < K; k0 += BKB) {
        #pragma unroll
        for (int w = 0; w < 2; ++w) {
            gload_lds16(pa0 + w * 64, dA0 + w * 8192);
            gload_lds16(pa1 + w * 64, dA1 + w * 8192);
            gload_lds16(pb0 + w * 64, dB0 + w * 8192);
            gload_lds16(pb1 + w * 64, dB1 + w * 8192);
        }
        pa0 += BKB; pa1 += BKB; pb0 += BKB; pb1 += BKB;
        __syncthreads();

        intx8 af[4], bg[4];
        #pragma unroll
        for (int t = 0; t < 4; ++t) {
            const intx4 alo = *(const intx4*)(As + aoff[t]);
            const intx4 ahi = *(const intx4*)(As + 8192 + aoff[t]);
            af[t] = __builtin_shufflevector(alo, ahi, 0, 1, 2, 3, 4, 5, 6, 7);
            const intx4 blo = *(const intx4*)(Bs + boff[t]);
            const intx4 bhi = *(const intx4*)(Bs + 8192 + boff[t]);
            bg[t] = __builtin_shufflevector(blo, bhi, 0, 1, 2, 3, 4, 5, 6, 7);
        }

        #pragma unroll
        for (int tm = 0; tm < 4; ++tm)
            #pragma unroll
            for (int tn = 0; tn < 4; ++tn)
                acc[tm][tn] = __builtin_amdgcn_mfma_scale_f32_16x16x128_f8f6f4(
                    af[tm], bg[tn], acc[tm][tn],
                    0, 0,          // cbsz = fp8 e4m3, blgp = fp8 e4m3
                    0, 127,        // A scale: 1.0
                    0, 127);       // B scale: 1.0
        __syncthreads();
    }

    // ---- epilogue: scale, capture diag, exp in place ----
    const int growb = bm * BM + wrow;
    const int gcolb = bn * BN + wcol;

    #pragma unroll
    for (int tm = 0; tm < 4; ++tm)
        #pragma unroll
        for (int tn = 0; tn < 4; ++tn)
            #pragma unroll
            for (int r = 0; r < 4; ++r) {
                const float l = acc[tm][tn][r] * scale;
                const int grow = growb + tm * 16 + quad * 4 + r;
                const int gcol = gcolb + tn * 16 + lanelo;
                if (grow == gcol) diag[grow] = l;
                acc[tm][tn][r] = __expf(l);
            }

    // ---- row sums ----
    #pragma unroll
    for (int tm = 0; tm < 4; ++tm) {
        floatx4 rs = acc[tm][0] + acc[tm][1] + acc[tm][2] + acc[tm][3];
        #pragma unroll
        for (int r = 0; r < 4; ++r) {
            float v = rs[r];
            v += __shfl_xor(v, 1);
            v += __shfl_xor(v, 2);
            v += __shfl_xor(v, 4);
            v += __shfl_xor(v, 8);
            if (lanelo == 0)
                atomicAdd(&rowsum[growb + tm * 16 + quad * 4 + r], v);
        }
    }

    // ---- col sums ----
    #pragma unroll
    for (int tn = 0; tn < 4; ++tn) {
        float cs = 0.f;
        #pragma unroll
        for (int tm = 0; tm < 4; ++tm)
            cs += acc[tm][tn][0] + acc[tm][tn][1] + acc[tm][tn][2] + acc[tm][tn][3];
        cs += __shfl_xor(cs, 16);
        cs += __shfl_xor(cs, 32);
        if (quad == 0)
            atomicAdd(&colsum[gcolb + tn * 16 + lanelo], cs);
    }

    // ---- last-block final reduction (replaces the final_reduce kernel) -----
    __threadfence();   // release our sums/diag to device scope
    __shared__ int lastflag;
    if (tid == 0) {
        const int old = atomicAdd(counter, 1);
        lastflag = (old == (int)gridDim.x - 1);
    }
    __syncthreads();
    if (!lastflag) return;
    __threadfence();   // acquire: all other blocks' sums/diag now visible

    float a = 0.f;
    for (int i = tid; i < N; i += 256) {
        const float rs = __hip_atomic_load(&rowsum[i], __ATOMIC_RELAXED, __HIP_MEMORY_SCOPE_AGENT);
        const float cs = __hip_atomic_load(&colsum[i], __ATOMIC_RELAXED, __HIP_MEMORY_SCOPE_AGENT);
        const float dg = __hip_atomic_load(&diag[i], __ATOMIC_RELAXED, __HIP_MEMORY_SCOPE_AGENT);
        a += 0.5f * (logf(rs) + logf(cs)) - dg;
    }
    #pragma unroll
    for (int o = 1; o < 64; o <<= 1) a += __shfl_xor(a, o);
    __shared__ float ws[4];
    if ((tid & 63) == 0) ws[tid >> 6] = a;
    __syncthreads();
    if (tid == 0) out[0] = (ws[0] + ws[1] + ws[2] + ws[3]) / (float)N;
}

extern "C" void kernel_launch(void* const* d_in, const int* in_sizes, int n_in,
                              void* d_out, int out_size, void* d_ws, size_t ws_size,
                              hipStream_t stream) {
    const float* img = (const float*)d_in[0];
    const float* txt = (const float*)d_in[1];
    float* out = (float*)d_out;

    const int D = 1024;
    const int N = in_sizes[0] / D;   // 8192

    unsigned char* imgq = (unsigned char*)d_ws;
    unsigned char* txtq = imgq + (size_t)N * D;
    float* rowsum = (float*)(txtq + (size_t)N * D);   // rowsum[N] ++ colsum[N]
    float* colsum = rowsum + N;
    float* diag = colsum + N;
    int* counter = (int*)(diag + N);

    normalize_fp8<<<2 * N / 4, 256, 0, stream>>>(img, txt, (unsigned int*)imgq,
                                                 (unsigned int*)txtq, rowsum,
                                                 counter, out, N);

    // acc = sum of (16a)(16b) = 256*cos; scale undoes 256 and applies 1/T.
    gemm_exp_kernel<<<(N / BM) * (N / BN), 256, 0, stream>>>(
        imgq, txtq, rowsum, colsum, diag, counter, out,
        N, D, 1.0f / (256.0f * 0.07f));
}

// Round 13
// 202.100 us; speedup vs baseline: 2.0348x; 2.0348x over previous
//
#include <hip/hip_runtime.h>

// ---------------------------------------------------------------------------
// ContrastiveLoss: loss = mean_i [ 0.5*(LSE_row_i + LSE_col_i) - diag_i ]
// over logits = normalize(img) @ normalize(txt)^T / 0.07, N=8192, D=1024.
// |logit| <= 14.29 -> exp() safe in fp32, no max subtraction needed.
//
// R12 = R10 (zero-conflict MX-fp8 16x16x128, GEMM 103.8us) + ONE change:
// explicit LDS double-buffering (4 distinct __shared__ arrays, K-loop
// unrolled x2). Each barrier now waits on staging issued a full compute
// phase earlier -> L2 latency hidden; stage/compute overlap to max() not
// sum(). Cost: 64KB LDS -> 2 blocks/CU.
// R11 lesson: XCD blockIdx swizzle assumed id%8~XCD; real dispatch mapping
// differs -> destroyed L2 locality, 3.2x regression (MfmaUtil 8%). The
// R10 2D grid (bm = blockIdx.x fast) already gives good per-XCD locality.
// R10 lesson: two-window LDS reads with quad pairs at identical in-window
// offsets 8192 apart collide; producer-side even/odd chunk interleave
// restores R5's zero-conflict geometry (slot = quad ^ ((row>>1)&3), b128
// at addr and addr+8192). R8: no-LDS thrashes L1. R9: occupancy not the
// limiter. R4: only b128 LDS reads are conflict-free under the 16B swizzle.
// R1: staging lane->addr must stay segment-monotone per quarter-wave.
// ---------------------------------------------------------------------------

#define BM 128
#define BN 128
#define BKB 128   // fp8 K-bytes per MFMA k-step

typedef float floatx4 __attribute__((ext_vector_type(4)));
typedef int   intx4   __attribute__((ext_vector_type(4)));
typedef int   intx8   __attribute__((ext_vector_type(8)));

__device__ __forceinline__ void gload_lds16(const unsigned char* g, unsigned char* lds) {
    __builtin_amdgcn_global_load_lds(
        (const __attribute__((address_space(1))) void*)g,
        (__attribute__((address_space(3))) void*)lds,
        16, 0, 0);
}

// ---- Kernel 1: row L2-normalize, x16, fp32 -> fp8 e4m3, chunk-interleaved --
// (R10 verbatim.) One wave per row, 4 rows/block. Rows [0,N)->img, [N,2N)->txt.
// Output dword d of a 256-dword row stored at d' = (d&~31)|(p*4+(d&3)),
// chunk c = (d>>2)&7, p = (c&1)*4 + (c>>1) (even chunks -> first 64B half).
// Side duty: zero rowsum/colsum (2N floats) and out.
__global__ __launch_bounds__(256)
void normalize_fp8(const float* __restrict__ img, const float* __restrict__ txt,
                   unsigned int* __restrict__ oimg, unsigned int* __restrict__ otxt,
                   float* __restrict__ sums, float* __restrict__ out, int N) {
    const int gi = blockIdx.x * 256 + threadIdx.x;
    if (gi < 2 * N) sums[gi] = 0.f;
    if (gi == 0) out[0] = 0.f;

    const int gw = blockIdx.x * 4 + (threadIdx.x >> 6);   // row id in [0,2N)
    const int lane = threadIdx.x & 63;
    const float* in = (gw < N) ? img : txt;
    unsigned int* o = (gw < N) ? oimg : otxt;
    const int row = (gw < N) ? gw : gw - N;
    const float4* rp = (const float4*)(in + (size_t)row * 1024);

    float4 v[4];
    float ss = 0.f;
    #pragma unroll
    for (int j = 0; j < 4; ++j) {
        v[j] = rp[j * 64 + lane];
        ss += v[j].x * v[j].x + v[j].y * v[j].y + v[j].z * v[j].z + v[j].w * v[j].w;
    }
    #pragma unroll
    for (int o2 = 1; o2 < 64; o2 <<= 1) ss += __shfl_xor(ss, o2);
    const float inv = 16.0f / fmaxf(sqrtf(ss), 1e-8f);   // x16 quantization scale
    #pragma unroll
    for (int j = 0; j < 4; ++j) {
        int p = __builtin_amdgcn_cvt_pk_fp8_f32(v[j].x * inv, v[j].y * inv, 0, false);
        p = __builtin_amdgcn_cvt_pk_fp8_f32(v[j].z * inv, v[j].w * inv, p, true);
        const int d = j * 64 + lane;
        const int c = (d >> 2) & 7;
        const int pp = (c & 1) * 4 + (c >> 1);
        const int dp = (d & ~31) | (pp * 4 + (d & 3));
        o[(size_t)row * 256 + dp] = (unsigned int)p;
    }
}

// ---- Kernel 2: 128x128 NT MX-fp8 GEMM, double-buffered LDS -----------------
__global__ __launch_bounds__(256)
void gemm_exp_kernel(const unsigned char* __restrict__ A,   // img_q [N][K] fp8 (interleaved)
                     const unsigned char* __restrict__ B,   // txt_q [N][K] fp8 (interleaved)
                     float* __restrict__ rowsum, float* __restrict__ colsum,
                     float* __restrict__ diag, int K, float scale) {
    // Each buffer: 2 windows x [128 rows][64B], slot = chunk ^ ((R>>1)&3).
    __shared__ unsigned char As0[2 * BM * 64];   // 16 KB
    __shared__ unsigned char As1[2 * BM * 64];
    __shared__ unsigned char Bs0[2 * BN * 64];
    __shared__ unsigned char Bs1[2 * BN * 64];   // total 64 KB

    const int bm = blockIdx.x, bn = blockIdx.y;
    const int tid = threadIdx.x;
    const int lane = tid & 63;
    const int wave = tid >> 6;
    const int quad = lane >> 4;
    const int lanelo = lane & 15;
    const int wrow = (wave >> 1) * 64;   // wave quadrant within 128x128
    const int wcol = (wave & 1) * 64;

    floatx4 acc[4][4] = {};

    // Staging (R7/R10 pattern): chunk c = wave*128 + lane (and +64);
    // LDS slot = c&3 of row c>>2; global chunk fetched = slot ^ swz(row).
    const int c0 = wave * 128 + lane;
    const int c1 = c0 + 64;
    const int r0 = c0 >> 2, r1 = c1 >> 2;
    const int kg0 = ((c0 & 3) ^ ((r0 >> 1) & 3)) * 16;   // byte in 64B window
    const int kg1 = ((c1 & 3) ^ ((r1 >> 1) & 3)) * 16;

    const unsigned char* pa0 = A + (size_t)bm * BM * K + (size_t)r0 * K + kg0;
    const unsigned char* pa1 = A + (size_t)bm * BM * K + (size_t)r1 * K + kg1;
    const unsigned char* pb0 = B + (size_t)bn * BN * K + (size_t)r0 * K + kg0;
    const unsigned char* pb1 = B + (size_t)bn * BN * K + (size_t)r1 * K + kg1;
    const int dofs0 = c0 * 16;
    const int dofs1 = c1 * 16;

    // Fragment LDS offsets (R5 geometry): slot = quad ^ swz(R) of one 64B
    // window; read1 = even chunks (k[32q..32q+16)), read2 = +8192 (odd).
    int aoff[4], boff[4];
    #pragma unroll
    for (int t = 0; t < 4; ++t) {
        const int Ra = wrow + t * 16 + lanelo;
        const int Rb = wcol + t * 16 + lanelo;
        aoff[t] = Ra * 64 + ((quad ^ ((Ra >> 1) & 3)) * 16);
        boff[t] = Rb * 64 + ((quad ^ ((Rb >> 1) & 3)) * 16);
    }

    auto stage = [&](unsigned char* SA, unsigned char* SB, int k) {
        #pragma unroll
        for (int w = 0; w < 2; ++w) {
            gload_lds16(pa0 + k + w * 64, SA + dofs0 + w * 8192);
            gload_lds16(pa1 + k + w * 64, SA + dofs1 + w * 8192);
            gload_lds16(pb0 + k + w * 64, SB + dofs0 + w * 8192);
            gload_lds16(pb1 + k + w * 64, SB + dofs1 + w * 8192);
        }
    };

    auto compute = [&](const unsigned char* SA, const unsigned char* SB) {
        intx8 af[4], bg[4];
        #pragma unroll
        for (int t = 0; t < 4; ++t) {
            const intx4 alo = *(const intx4*)(SA + aoff[t]);
            const intx4 ahi = *(const intx4*)(SA + 8192 + aoff[t]);
            af[t] = __builtin_shufflevector(alo, ahi, 0, 1, 2, 3, 4, 5, 6, 7);
            const intx4 blo = *(const intx4*)(SB + boff[t]);
            const intx4 bhi = *(const intx4*)(SB + 8192 + boff[t]);
            bg[t] = __builtin_shufflevector(blo, bhi, 0, 1, 2, 3, 4, 5, 6, 7);
        }
        #pragma unroll
        for (int tm = 0; tm < 4; ++tm)
            #pragma unroll
            for (int tn = 0; tn < 4; ++tn)
                acc[tm][tn] = __builtin_amdgcn_mfma_scale_f32_16x16x128_f8f6f4(
                    af[tm], bg[tn], acc[tm][tn],
                    0, 0,          // cbsz = fp8 e4m3, blgp = fp8 e4m3
                    0, 127,        // A scale: 1.0
                    0, 127);       // B scale: 1.0
    };

    stage(As0, Bs0, 0);
    for (int k = 0; k < K; k += 2 * BKB) {
        __syncthreads();                       // As0/Bs0 staged (prev phase)
        if (k + BKB < K) stage(As1, Bs1, k + BKB);
        compute(As0, Bs0);
        __syncthreads();                       // As1/Bs1 staged; As0 free
        if (k + 2 * BKB < K) stage(As0, Bs0, k + 2 * BKB);
        compute(As1, Bs1);
    }

    // ---- epilogue: scale, capture diag, exp in place ----
    const int growb = bm * BM + wrow;
    const int gcolb = bn * BN + wcol;

    #pragma unroll
    for (int tm = 0; tm < 4; ++tm)
        #pragma unroll
        for (int tn = 0; tn < 4; ++tn)
            #pragma unroll
            for (int r = 0; r < 4; ++r) {
                const float l = acc[tm][tn][r] * scale;
                const int grow = growb + tm * 16 + quad * 4 + r;
                const int gcol = gcolb + tn * 16 + lanelo;
                if (grow == gcol) diag[grow] = l;
                acc[tm][tn][r] = __expf(l);
            }

    // ---- row sums: reduce over the 16 lanes sharing a row, then atomicAdd ----
    #pragma unroll
    for (int tm = 0; tm < 4; ++tm) {
        floatx4 rs = acc[tm][0] + acc[tm][1] + acc[tm][2] + acc[tm][3];
        #pragma unroll
        for (int r = 0; r < 4; ++r) {
            float v = rs[r];
            v += __shfl_xor(v, 1);
            v += __shfl_xor(v, 2);
            v += __shfl_xor(v, 4);
            v += __shfl_xor(v, 8);
            if (lanelo == 0)
                atomicAdd(&rowsum[growb + tm * 16 + quad * 4 + r], v);
        }
    }

    // ---- col sums: reduce over quads (xor 16, 32), then atomicAdd ----
    #pragma unroll
    for (int tn = 0; tn < 4; ++tn) {
        float cs = 0.f;
        #pragma unroll
        for (int tm = 0; tm < 4; ++tm)
            cs += acc[tm][tn][0] + acc[tm][tn][1] + acc[tm][tn][2] + acc[tm][tn][3];
        cs += __shfl_xor(cs, 16);
        cs += __shfl_xor(cs, 32);
        if (quad == 0)
            atomicAdd(&colsum[gcolb + tn * 16 + lanelo], cs);
    }
}

// ---- Kernel 3: loss = mean( 0.5*(log(rowsum)+log(colsum)) - diag ) ---------
// out zeroed by normalize_fp8 (stream-ordered before this kernel).
__global__ __launch_bounds__(256)
void final_reduce(const float* __restrict__ rowsum, const float* __restrict__ colsum,
                  const float* __restrict__ diag, float* __restrict__ out, int n) {
    const int i = blockIdx.x * 256 + threadIdx.x;
    const int t = threadIdx.x;
    float v = 0.5f * (logf(rowsum[i]) + logf(colsum[i])) - diag[i];
    #pragma unroll
    for (int o = 1; o < 64; o <<= 1) v += __shfl_xor(v, o);
    __shared__ float ws[4];
    if ((t & 63) == 0) ws[t >> 6] = v;
    __syncthreads();
    if (t == 0) atomicAdd(out, (ws[0] + ws[1] + ws[2] + ws[3]) / (float)n);
}

extern "C" void kernel_launch(void* const* d_in, const int* in_sizes, int n_in,
                              void* d_out, int out_size, void* d_ws, size_t ws_size,
                              hipStream_t stream) {
    const float* img = (const float*)d_in[0];
    const float* txt = (const float*)d_in[1];
    float* out = (float*)d_out;

    const int D = 1024;
    const int N = in_sizes[0] / D;   // 8192

    unsigned char* imgq = (unsigned char*)d_ws;
    unsigned char* txtq = imgq + (size_t)N * D;
    float* rowsum = (float*)(txtq + (size_t)N * D);   // rowsum[N] ++ colsum[N]
    float* colsum = rowsum + N;
    float* diag = colsum + N;

    normalize_fp8<<<2 * N / 4, 256, 0, stream>>>(img, txt, (unsigned int*)imgq,
                                                 (unsigned int*)txtq, rowsum, out, N);

    dim3 grid(N / BM, N / BN);
    // acc = sum of (16a)(16b) = 256*cos; scale undoes 256 and applies 1/T.
    gemm_exp_kernel<<<grid, 256, 0, stream>>>(imgq, txtq, rowsum, colsum, diag,
                                              D, 1.0f / (256.0f * 0.07f));
    final_reduce<<<N / 256, 256, 0, stream>>>(rowsum, colsum, diag, out, N);
}

// Round 14
// 191.383 us; speedup vs baseline: 2.1487x; 1.0560x over previous
//
#include <hip/hip_runtime.h>

// ---------------------------------------------------------------------------
// ContrastiveLoss: loss = mean_i [ 0.5*(LSE_row_i + LSE_col_i) - diag_i ]
// over logits = normalize(img) @ normalize(txt)^T / 0.07, N=8192, D=1024.
// |logit| <= 14.29 -> exp() safe in fp32, no max subtraction needed.
//
// R13 = R10 (zero-conflict MX-fp8 16x16x128, GEMM 103.8us) + ONE change:
// XCD-inverted block swizzle. Under round-robin id->XCD (id&7 heuristic),
// xcd = id&7 selects the bm strip (8 A panels = 1MB, L2-resident per XCD);
// within an XCD, blocks walk bn in 8-wide super-groups -> resident B ~20
// panels (2.5MB). Per-XCD L2 set ~3.5MB < 4MB. Downside bounded: any
// contiguous id window touches <= A-full + 20 B panels = R10's set.
// R11 lesson: the old swizzle sprayed every super-tile across all XCDs
// (40MB/XCD -> 3.2x regression). R12 lesson: explicit LDS dbuf costs
// occupancy (29->21%) and regresses; implicit wave overlap wins (m99/m100).
// R10 lesson: producer-side even/odd chunk interleave -> R5 zero-conflict
// LDS geometry (slot = quad ^ ((row>>1)&3), b128 at addr, addr+8192).
// R8: no-LDS thrashes L1. R9: occupancy not the limiter. R4: only b128 LDS
// reads are conflict-free under the 16B swizzle. R1: staging lane->addr
// segment-monotone per quarter-wave.
// ---------------------------------------------------------------------------

#define BM 128
#define BN 128
#define BKB 128   // fp8 K-bytes per iteration (one MFMA k-step)

typedef float floatx4 __attribute__((ext_vector_type(4)));
typedef int   intx4   __attribute__((ext_vector_type(4)));
typedef int   intx8   __attribute__((ext_vector_type(8)));

__device__ __forceinline__ void gload_lds16(const unsigned char* g, unsigned char* lds) {
    __builtin_amdgcn_global_load_lds(
        (const __attribute__((address_space(1))) void*)g,
        (__attribute__((address_space(3))) void*)lds,
        16, 0, 0);
}

// ---- Kernel 1: row L2-normalize, x16, fp32 -> fp8 e4m3, chunk-interleaved --
// (R10 verbatim.) One wave per row, 4 rows/block. Rows [0,N)->img, [N,2N)->txt.
// Output dword d of a 256-dword row stored at d' = (d&~31)|(p*4+(d&3)),
// chunk c = (d>>2)&7, p = (c&1)*4 + (c>>1) (even chunks -> first 64B half).
// Side duty: zero rowsum/colsum (2N floats) and out.
__global__ __launch_bounds__(256)
void normalize_fp8(const float* __restrict__ img, const float* __restrict__ txt,
                   unsigned int* __restrict__ oimg, unsigned int* __restrict__ otxt,
                   float* __restrict__ sums, float* __restrict__ out, int N) {
    const int gi = blockIdx.x * 256 + threadIdx.x;
    if (gi < 2 * N) sums[gi] = 0.f;
    if (gi == 0) out[0] = 0.f;

    const int gw = blockIdx.x * 4 + (threadIdx.x >> 6);   // row id in [0,2N)
    const int lane = threadIdx.x & 63;
    const float* in = (gw < N) ? img : txt;
    unsigned int* o = (gw < N) ? oimg : otxt;
    const int row = (gw < N) ? gw : gw - N;
    const float4* rp = (const float4*)(in + (size_t)row * 1024);

    float4 v[4];
    float ss = 0.f;
    #pragma unroll
    for (int j = 0; j < 4; ++j) {
        v[j] = rp[j * 64 + lane];
        ss += v[j].x * v[j].x + v[j].y * v[j].y + v[j].z * v[j].z + v[j].w * v[j].w;
    }
    #pragma unroll
    for (int o2 = 1; o2 < 64; o2 <<= 1) ss += __shfl_xor(ss, o2);
    const float inv = 16.0f / fmaxf(sqrtf(ss), 1e-8f);   // x16 quantization scale
    #pragma unroll
    for (int j = 0; j < 4; ++j) {
        int p = __builtin_amdgcn_cvt_pk_fp8_f32(v[j].x * inv, v[j].y * inv, 0, false);
        p = __builtin_amdgcn_cvt_pk_fp8_f32(v[j].z * inv, v[j].w * inv, p, true);
        const int d = j * 64 + lane;
        const int c = (d >> 2) & 7;
        const int pp = (c & 1) * 4 + (c >> 1);
        const int dp = (d & ~31) | (pp * 4 + (d & 3));
        o[(size_t)row * 256 + dp] = (unsigned int)p;
    }
}

// ---- Kernel 2: 128x128-tile NT MX-fp8 GEMM + fused exp/row-col sums/diag ---
__global__ __launch_bounds__(256)
void gemm_exp_kernel(const unsigned char* __restrict__ A,   // img_q [N][K] fp8 (interleaved)
                     const unsigned char* __restrict__ B,   // txt_q [N][K] fp8 (interleaved)
                     float* __restrict__ rowsum, float* __restrict__ colsum,
                     float* __restrict__ diag, int K, float scale) {
    // XCD-inverted swizzle: xcd = id&7 owns bm strip [xcd*8, xcd*8+8);
    // within XCD, bn walks in 8-wide super-groups.
    const int id = blockIdx.x;
    const int idp = id >> 3;            // position within XCD's sequence
    const int pos = idp & 63;
    const int bm = (id & 7) * 8 + (pos & 7);
    const int bn = (idp >> 6) * 8 + (pos >> 3);

    // LDS: per matrix, 2 windows x [128 rows][64B], slot = chunk ^ ((R>>1)&3).
    __shared__ unsigned char As[2 * BM * 64];   // 16 KB
    __shared__ unsigned char Bs[2 * BN * 64];   // 16 KB

    const int tid = threadIdx.x;
    const int lane = tid & 63;
    const int wave = tid >> 6;
    const int quad = lane >> 4;
    const int lanelo = lane & 15;
    const int wrow = (wave >> 1) * 64;   // wave quadrant within 128x128
    const int wcol = (wave & 1) * 64;

    floatx4 acc[4][4] = {};

    // Staging (R7 pattern): chunk c = wave*128 + lane (and +64); LDS slot =
    // c&3 of row c>>2; global chunk fetched = slot ^ swz(row).
    const int c0 = wave * 128 + lane;
    const int c1 = c0 + 64;
    const int r0 = c0 >> 2, r1 = c1 >> 2;
    const int kg0 = ((c0 & 3) ^ ((r0 >> 1) & 3)) * 16;   // byte in 64B window
    const int kg1 = ((c1 & 3) ^ ((r1 >> 1) & 3)) * 16;

    const unsigned char* pa0 = A + (size_t)bm * BM * K + (size_t)r0 * K + kg0;
    const unsigned char* pa1 = A + (size_t)bm * BM * K + (size_t)r1 * K + kg1;
    const unsigned char* pb0 = B + (size_t)bn * BN * K + (size_t)r0 * K + kg0;
    const unsigned char* pb1 = B + (size_t)bn * BN * K + (size_t)r1 * K + kg1;
    unsigned char* dA0 = As + c0 * 16;
    unsigned char* dA1 = As + c1 * 16;
    unsigned char* dB0 = Bs + c0 * 16;
    unsigned char* dB1 = Bs + c1 * 16;

    // Fragment LDS offsets (R5 geometry): slot = quad ^ swz(R) of one 64B
    // window; read1 = even chunks (k[32q..32q+16)), read2 = +8192 (odd).
    int aoff[4], boff[4];
    #pragma unroll
    for (int t = 0; t < 4; ++t) {
        const int Ra = wrow + t * 16 + lanelo;
        const int Rb = wcol + t * 16 + lanelo;
        aoff[t] = Ra * 64 + ((quad ^ ((Ra >> 1) & 3)) * 16);
        boff[t] = Rb * 64 + ((quad ^ ((Rb >> 1) & 3)) * 16);
    }

    for (int k0 = 0; k0 < K; k0 += BKB) {
        #pragma unroll
        for (int w = 0; w < 2; ++w) {
            gload_lds16(pa0 + w * 64, dA0 + w * 8192);
            gload_lds16(pa1 + w * 64, dA1 + w * 8192);
            gload_lds16(pb0 + w * 64, dB0 + w * 8192);
            gload_lds16(pb1 + w * 64, dB1 + w * 8192);
        }
        pa0 += BKB; pa1 += BKB; pb0 += BKB; pb1 += BKB;
        __syncthreads();

        intx8 af[4], bg[4];
        #pragma unroll
        for (int t = 0; t < 4; ++t) {
            const intx4 alo = *(const intx4*)(As + aoff[t]);
            const intx4 ahi = *(const intx4*)(As + 8192 + aoff[t]);
            af[t] = __builtin_shufflevector(alo, ahi, 0, 1, 2, 3, 4, 5, 6, 7);
            const intx4 blo = *(const intx4*)(Bs + boff[t]);
            const intx4 bhi = *(const intx4*)(Bs + 8192 + boff[t]);
            bg[t] = __builtin_shufflevector(blo, bhi, 0, 1, 2, 3, 4, 5, 6, 7);
        }

        #pragma unroll
        for (int tm = 0; tm < 4; ++tm)
            #pragma unroll
            for (int tn = 0; tn < 4; ++tn)
                acc[tm][tn] = __builtin_amdgcn_mfma_scale_f32_16x16x128_f8f6f4(
                    af[tm], bg[tn], acc[tm][tn],
                    0, 0,          // cbsz = fp8 e4m3, blgp = fp8 e4m3
                    0, 127,        // A scale: 1.0
                    0, 127);       // B scale: 1.0
        __syncthreads();
    }

    // ---- epilogue: scale, capture diag, exp in place ----
    const int growb = bm * BM + wrow;
    const int gcolb = bn * BN + wcol;

    #pragma unroll
    for (int tm = 0; tm < 4; ++tm)
        #pragma unroll
        for (int tn = 0; tn < 4; ++tn)
            #pragma unroll
            for (int r = 0; r < 4; ++r) {
                const float l = acc[tm][tn][r] * scale;
                const int grow = growb + tm * 16 + quad * 4 + r;
                const int gcol = gcolb + tn * 16 + lanelo;
                if (grow == gcol) diag[grow] = l;
                acc[tm][tn][r] = __expf(l);
            }

    // ---- row sums: reduce over the 16 lanes sharing a row, then atomicAdd ----
    #pragma unroll
    for (int tm = 0; tm < 4; ++tm) {
        floatx4 rs = acc[tm][0] + acc[tm][1] + acc[tm][2] + acc[tm][3];
        #pragma unroll
        for (int r = 0; r < 4; ++r) {
            float v = rs[r];
            v += __shfl_xor(v, 1);
            v += __shfl_xor(v, 2);
            v += __shfl_xor(v, 4);
            v += __shfl_xor(v, 8);
            if (lanelo == 0)
                atomicAdd(&rowsum[growb + tm * 16 + quad * 4 + r], v);
        }
    }

    // ---- col sums: reduce over quads (xor 16, 32), then atomicAdd ----
    #pragma unroll
    for (int tn = 0; tn < 4; ++tn) {
        float cs = 0.f;
        #pragma unroll
        for (int tm = 0; tm < 4; ++tm)
            cs += acc[tm][tn][0] + acc[tm][tn][1] + acc[tm][tn][2] + acc[tm][tn][3];
        cs += __shfl_xor(cs, 16);
        cs += __shfl_xor(cs, 32);
        if (quad == 0)
            atomicAdd(&colsum[gcolb + tn * 16 + lanelo], cs);
    }
}

// ---- Kernel 3: loss = mean( 0.5*(log(rowsum)+log(colsum)) - diag ) ---------
// out zeroed by normalize_fp8 (stream-ordered before this kernel).
__global__ __launch_bounds__(256)
void final_reduce(const float* __restrict__ rowsum, const float* __restrict__ colsum,
                  const float* __restrict__ diag, float* __restrict__ out, int n) {
    const int i = blockIdx.x * 256 + threadIdx.x;
    const int t = threadIdx.x;
    float v = 0.5f * (logf(rowsum[i]) + logf(colsum[i])) - diag[i];
    #pragma unroll
    for (int o = 1; o < 64; o <<= 1) v += __shfl_xor(v, o);
    __shared__ float ws[4];
    if ((t & 63) == 0) ws[t >> 6] = v;
    __syncthreads();
    if (t == 0) atomicAdd(out, (ws[0] + ws[1] + ws[2] + ws[3]) / (float)n);
}

extern "C" void kernel_launch(void* const* d_in, const int* in_sizes, int n_in,
                              void* d_out, int out_size, void* d_ws, size_t ws_size,
                              hipStream_t stream) {
    const float* img = (const float*)d_in[0];
    const float* txt = (const float*)d_in[1];
    float* out = (float*)d_out;

    const int D = 1024;
    const int N = in_sizes[0] / D;   // 8192

    unsigned char* imgq = (unsigned char*)d_ws;
    unsigned char* txtq = imgq + (size_t)N * D;
    float* rowsum = (float*)(txtq + (size_t)N * D);   // rowsum[N] ++ colsum[N]
    float* colsum = rowsum + N;
    float* diag = colsum + N;

    normalize_fp8<<<2 * N / 4, 256, 0, stream>>>(img, txt, (unsigned int*)imgq,
                                                 (unsigned int*)txtq, rowsum, out, N);

    // acc = sum of (16a)(16b) = 256*cos; scale undoes 256 and applies 1/T.
    gemm_exp_kernel<<<(N / BM) * (N / BN), 256, 0, stream>>>(
        imgq, txtq, rowsum, colsum, diag, D, 1.0f / (256.0f * 0.07f));
    final_reduce<<<N / 256, 256, 0, stream>>>(rowsum, colsum, diag, out, N);
}

// Round 15
// 186.923 us; speedup vs baseline: 2.2000x; 1.0239x over previous
//
#include <hip/hip_runtime.h>

// ---------------------------------------------------------------------------
// ContrastiveLoss: loss = mean_i [ 0.5*(LSE_row_i + LSE_col_i) - diag_i ]
// over logits = normalize(img) @ normalize(txt)^T / 0.07, N=8192, D=1024.
// |logit| <= 14.29 -> exp() safe in fp32, no max subtraction needed.
//
// R14 = R13 + ONE change: barrier reorder (same-buffer prefetch).
// Old: stage(k); syncA; reads; MFMA; syncB  -> staging latency fully exposed
// at syncA (vmcnt(0) drain right after issue).
// New: syncA (stage(k) landed); reads; syncB (reads done, LDS reusable);
// stage(k+1); MFMA  -> staging gets the whole MFMA phase to land before the
// next syncA. R12's dbuf benefit without the 64KB/occupancy cost.
// Cycle model (R13): per block-iter 768 cyc LDS-reads + 260 staging-writes
// + 484 MFMA(overlap) vs 1670 observed -> ~600 cyc barrier stall to recover.
// Carried: R13 inverted XCD swizzle (neutral-to-+2%); R10 producer-side
// even/odd chunk interleave -> zero-conflict b128 LDS reads (slot = quad ^
// ((row>>1)&3), pair at addr/addr+8192); R12 - explicit dbuf regresses via
// occupancy; R11 - wrong swizzle sprays L2 (3.2x); R8 - no-LDS thrashes L1;
// R4 - only b128 is conflict-free under 16B swizzle; R1 - staging
// lane->addr segment-monotone per quarter-wave.
// ---------------------------------------------------------------------------

#define BM 128
#define BN 128
#define BKB 128   // fp8 K-bytes per iteration (one MFMA k-step)

typedef float floatx4 __attribute__((ext_vector_type(4)));
typedef int   intx4   __attribute__((ext_vector_type(4)));
typedef int   intx8   __attribute__((ext_vector_type(8)));

__device__ __forceinline__ void gload_lds16(const unsigned char* g, unsigned char* lds) {
    __builtin_amdgcn_global_load_lds(
        (const __attribute__((address_space(1))) void*)g,
        (__attribute__((address_space(3))) void*)lds,
        16, 0, 0);
}

// ---- Kernel 1: row L2-normalize, x16, fp32 -> fp8 e4m3, chunk-interleaved --
// One wave per row, 4 rows/block. Rows [0,N)->img, [N,2N)->txt.
// Output dword d of a 256-dword row stored at d' = (d&~31)|(p*4+(d&3)),
// chunk c = (d>>2)&7, p = (c&1)*4 + (c>>1) (even chunks -> first 64B half).
// Side duty: zero rowsum/colsum (2N floats) and out.
__global__ __launch_bounds__(256)
void normalize_fp8(const float* __restrict__ img, const float* __restrict__ txt,
                   unsigned int* __restrict__ oimg, unsigned int* __restrict__ otxt,
                   float* __restrict__ sums, float* __restrict__ out, int N) {
    const int gi = blockIdx.x * 256 + threadIdx.x;
    if (gi < 2 * N) sums[gi] = 0.f;
    if (gi == 0) out[0] = 0.f;

    const int gw = blockIdx.x * 4 + (threadIdx.x >> 6);   // row id in [0,2N)
    const int lane = threadIdx.x & 63;
    const float* in = (gw < N) ? img : txt;
    unsigned int* o = (gw < N) ? oimg : otxt;
    const int row = (gw < N) ? gw : gw - N;
    const float4* rp = (const float4*)(in + (size_t)row * 1024);

    float4 v[4];
    float ss = 0.f;
    #pragma unroll
    for (int j = 0; j < 4; ++j) {
        v[j] = rp[j * 64 + lane];
        ss += v[j].x * v[j].x + v[j].y * v[j].y + v[j].z * v[j].z + v[j].w * v[j].w;
    }
    #pragma unroll
    for (int o2 = 1; o2 < 64; o2 <<= 1) ss += __shfl_xor(ss, o2);
    const float inv = 16.0f / fmaxf(sqrtf(ss), 1e-8f);   // x16 quantization scale
    #pragma unroll
    for (int j = 0; j < 4; ++j) {
        int p = __builtin_amdgcn_cvt_pk_fp8_f32(v[j].x * inv, v[j].y * inv, 0, false);
        p = __builtin_amdgcn_cvt_pk_fp8_f32(v[j].z * inv, v[j].w * inv, p, true);
        const int d = j * 64 + lane;
        const int c = (d >> 2) & 7;
        const int pp = (c & 1) * 4 + (c >> 1);
        const int dp = (d & ~31) | (pp * 4 + (d & 3));
        o[(size_t)row * 256 + dp] = (unsigned int)p;
    }
}

// ---- Kernel 2: 128x128-tile NT MX-fp8 GEMM + fused exp/row-col sums/diag ---
__global__ __launch_bounds__(256)
void gemm_exp_kernel(const unsigned char* __restrict__ A,   // img_q [N][K] fp8 (interleaved)
                     const unsigned char* __restrict__ B,   // txt_q [N][K] fp8 (interleaved)
                     float* __restrict__ rowsum, float* __restrict__ colsum,
                     float* __restrict__ diag, int K, float scale) {
    // XCD-inverted swizzle (R13): xcd = id&7 owns bm strip [xcd*8, xcd*8+8).
    const int id = blockIdx.x;
    const int idp = id >> 3;            // position within XCD's sequence
    const int pos = idp & 63;
    const int bm = (id & 7) * 8 + (pos & 7);
    const int bn = (idp >> 6) * 8 + (pos >> 3);

    // LDS: per matrix, 2 windows x [128 rows][64B], slot = chunk ^ ((R>>1)&3).
    __shared__ unsigned char As[2 * BM * 64];   // 16 KB
    __shared__ unsigned char Bs[2 * BN * 64];   // 16 KB

    const int tid = threadIdx.x;
    const int lane = tid & 63;
    const int wave = tid >> 6;
    const int quad = lane >> 4;
    const int lanelo = lane & 15;
    const int wrow = (wave >> 1) * 64;   // wave quadrant within 128x128
    const int wcol = (wave & 1) * 64;

    floatx4 acc[4][4] = {};

    // Staging (R7 pattern): chunk c = wave*128 + lane (and +64); LDS slot =
    // c&3 of row c>>2; global chunk fetched = slot ^ swz(row).
    const int c0 = wave * 128 + lane;
    const int c1 = c0 + 64;
    const int r0 = c0 >> 2, r1 = c1 >> 2;
    const int kg0 = ((c0 & 3) ^ ((r0 >> 1) & 3)) * 16;   // byte in 64B window
    const int kg1 = ((c1 & 3) ^ ((r1 >> 1) & 3)) * 16;

    const unsigned char* pa0 = A + (size_t)bm * BM * K + (size_t)r0 * K + kg0;
    const unsigned char* pa1 = A + (size_t)bm * BM * K + (size_t)r1 * K + kg1;
    const unsigned char* pb0 = B + (size_t)bn * BN * K + (size_t)r0 * K + kg0;
    const unsigned char* pb1 = B + (size_t)bn * BN * K + (size_t)r1 * K + kg1;
    unsigned char* dA0 = As + c0 * 16;
    unsigned char* dA1 = As + c1 * 16;
    unsigned char* dB0 = Bs + c0 * 16;
    unsigned char* dB1 = Bs + c1 * 16;

    // Fragment LDS offsets (R5 geometry): slot = quad ^ swz(R) of one 64B
    // window; read1 = even chunks (k[32q..32q+16)), read2 = +8192 (odd).
    int aoff[4], boff[4];
    #pragma unroll
    for (int t = 0; t < 4; ++t) {
        const int Ra = wrow + t * 16 + lanelo;
        const int Rb = wcol + t * 16 + lanelo;
        aoff[t] = Ra * 64 + ((quad ^ ((Ra >> 1) & 3)) * 16);
        boff[t] = Rb * 64 + ((quad ^ ((Rb >> 1) & 3)) * 16);
    }

    auto stage = [&](int k) {
        #pragma unroll
        for (int w = 0; w < 2; ++w) {
            gload_lds16(pa0 + k + w * 64, dA0 + w * 8192);
            gload_lds16(pa1 + k + w * 64, dA1 + w * 8192);
            gload_lds16(pb0 + k + w * 64, dB0 + w * 8192);
            gload_lds16(pb1 + k + w * 64, dB1 + w * 8192);
        }
    };

    stage(0);
    for (int k = 0; k < K; k += BKB) {
        __syncthreads();                 // staging(k) landed in LDS
        intx8 af[4], bg[4];
        #pragma unroll
        for (int t = 0; t < 4; ++t) {
            const intx4 alo = *(const intx4*)(As + aoff[t]);
            const intx4 ahi = *(const intx4*)(As + 8192 + aoff[t]);
            af[t] = __builtin_shufflevector(alo, ahi, 0, 1, 2, 3, 4, 5, 6, 7);
            const intx4 blo = *(const intx4*)(Bs + boff[t]);
            const intx4 bhi = *(const intx4*)(Bs + 8192 + boff[t]);
            bg[t] = __builtin_shufflevector(blo, bhi, 0, 1, 2, 3, 4, 5, 6, 7);
        }
        __syncthreads();                 // all waves' reads done; LDS free
        if (k + BKB < K) stage(k + BKB); // prefetch next tile behind MFMA

        #pragma unroll
        for (int tm = 0; tm < 4; ++tm)
            #pragma unroll
            for (int tn = 0; tn < 4; ++tn)
                acc[tm][tn] = __builtin_amdgcn_mfma_scale_f32_16x16x128_f8f6f4(
                    af[tm], bg[tn], acc[tm][tn],
                    0, 0,          // cbsz = fp8 e4m3, blgp = fp8 e4m3
                    0, 127,        // A scale: 1.0
                    0, 127);       // B scale: 1.0
    }

    // ---- epilogue: scale, capture diag, exp in place ----
    const int growb = bm * BM + wrow;
    const int gcolb = bn * BN + wcol;

    #pragma unroll
    for (int tm = 0; tm < 4; ++tm)
        #pragma unroll
        for (int tn = 0; tn < 4; ++tn)
            #pragma unroll
            for (int r = 0; r < 4; ++r) {
                const float l = acc[tm][tn][r] * scale;
                const int grow = growb + tm * 16 + quad * 4 + r;
                const int gcol = gcolb + tn * 16 + lanelo;
                if (grow == gcol) diag[grow] = l;
                acc[tm][tn][r] = __expf(l);
            }

    // ---- row sums: reduce over the 16 lanes sharing a row, then atomicAdd ----
    #pragma unroll
    for (int tm = 0; tm < 4; ++tm) {
        floatx4 rs = acc[tm][0] + acc[tm][1] + acc[tm][2] + acc[tm][3];
        #pragma unroll
        for (int r = 0; r < 4; ++r) {
            float v = rs[r];
            v += __shfl_xor(v, 1);
            v += __shfl_xor(v, 2);
            v += __shfl_xor(v, 4);
            v += __shfl_xor(v, 8);
            if (lanelo == 0)
                atomicAdd(&rowsum[growb + tm * 16 + quad * 4 + r], v);
        }
    }

    // ---- col sums: reduce over quads (xor 16, 32), then atomicAdd ----
    #pragma unroll
    for (int tn = 0; tn < 4; ++tn) {
        float cs = 0.f;
        #pragma unroll
        for (int tm = 0; tm < 4; ++tm)
            cs += acc[tm][tn][0] + acc[tm][tn][1] + acc[tm][tn][2] + acc[tm][tn][3];
        cs += __shfl_xor(cs, 16);
        cs += __shfl_xor(cs, 32);
        if (quad == 0)
            atomicAdd(&colsum[gcolb + tn * 16 + lanelo], cs);
    }
}

// ---- Kernel 3: loss = mean( 0.5*(log(rowsum)+log(colsum)) - diag ) ---------
// out zeroed by normalize_fp8 (stream-ordered before this kernel).
__global__ __launch_bounds__(256)
void final_reduce(const float* __restrict__ rowsum, const float* __restrict__ colsum,
                  const float* __restrict__ diag, float* __restrict__ out, int n) {
    const int i = blockIdx.x * 256 + threadIdx.x;
    const int t = threadIdx.x;
    float v = 0.5f * (logf(rowsum[i]) + logf(colsum[i])) - diag[i];
    #pragma unroll
    for (int o = 1; o < 64; o <<= 1) v += __shfl_xor(v, o);
    __shared__ float ws[4];
    if ((t & 63) == 0) ws[t >> 6] = v;
    __syncthreads();
    if (t == 0) atomicAdd(out, (ws[0] + ws[1] + ws[2] + ws[3]) / (float)n);
}

extern "C" void kernel_launch(void* const* d_in, const int* in_sizes, int n_in,
                              void* d_out, int out_size, void* d_ws, size_t ws_size,
                              hipStream_t stream) {
    const float* img = (const float*)d_in[0];
    const float* txt = (const float*)d_in[1];
    float* out = (float*)d_out;

    const int D = 1024;
    const int N = in_sizes[0] / D;   // 8192

    unsigned char* imgq = (unsigned char*)d_ws;
    unsigned char* txtq = imgq + (size_t)N * D;
    float* rowsum = (float*)(txtq + (size_t)N * D);   // rowsum[N] ++ colsum[N]
    float* colsum = rowsum + N;
    float* diag = colsum + N;

    normalize_fp8<<<2 * N / 4, 256, 0, stream>>>(img, txt, (unsigned int*)imgq,
                                                 (unsigned int*)txtq, rowsum, out, N);

    // acc = sum of (16a)(16b) = 256*cos; scale undoes 256 and applies 1/T.
    gemm_exp_kernel<<<(N / BM) * (N / BN), 256, 0, stream>>>(
        imgq, txtq, rowsum, colsum, diag, D, 1.0f / (256.0f * 0.07f));
    final_reduce<<<N / 256, 256, 0, stream>>>(rowsum, colsum, diag, out, N);
}